// Round 1
// baseline (130.805 us; speedup 1.0000x reference)
//
#include <hip/hip_runtime.h>

#define TOKENS 8192
#define EXPERTS 64
#define HIDDEN 4096

// ---------------------------------------------------------------------------
// Kernel A: transpose weight [64][4096] -> wT [4096][64] (f32, 1 MB)
// so that per-k expert weights are contiguous + wave-uniform in the main loop.
// ---------------------------------------------------------------------------
__global__ void transpose_w_kernel(const float* __restrict__ w,
                                   float* __restrict__ wT) {
    int idx = blockIdx.x * 256 + threadIdx.x;     // 0 .. 64*4096-1
    int k = idx >> 6;                             // hidden index
    int e = idx & 63;                             // expert index
    wT[idx] = w[e * HIDDEN + k];                  // write coalesced
}

// ---------------------------------------------------------------------------
// Kernel B: partial logits.
// Grid: 128 token-groups * SPLIT k-segments, block = 64 threads (1 wave).
// lane = token within group; acc[64] = accumulator per expert.
// Per k: 1 ds_read (x broadcast-free), 64 v_fmac with wave-uniform weights
// (expected to live in SGPRs via s_load of the transposed weight row).
// ---------------------------------------------------------------------------
__global__ void logits_partial_kernel(const float* __restrict__ x,
                                      const float* __restrict__ wT,
                                      float* __restrict__ part,
                                      int split, int ks) {
    __shared__ float xs[64 * 65];                 // [k within chunk][token], +1 pad
    const int lane = threadIdx.x;                 // 0..63, token offset in group
    const int g = blockIdx.x / split;             // token group
    const int s = blockIdx.x % split;             // k segment
    const int t0 = g * 64;
    const int k0 = s * ks;

    float acc[EXPERTS];
#pragma unroll
    for (int e = 0; e < EXPERTS; ++e) acc[e] = 0.0f;

    for (int kc = 0; kc < ks; kc += 64) {
        __syncthreads();
        // stage x[t0..t0+63][k0+kc .. k0+kc+63] into xs[k][token]
        // global read: lanes contiguous over k (coalesced 256B per row)
        // LDS write: stride 65 -> conflict-free
#pragma unroll 8
        for (int tt = 0; tt < 64; ++tt) {
            xs[lane * 65 + tt] = x[(size_t)(t0 + tt) * HIDDEN + (k0 + kc + lane)];
        }
        __syncthreads();

        for (int k = 0; k < 64; ++k) {
            const float xv = xs[k * 65 + lane];
            const float* __restrict__ wrow = wT + (size_t)(k0 + kc + k) * 64;
#pragma unroll
            for (int eh = 0; eh < EXPERTS; eh += 32) {
#pragma unroll
                for (int e = 0; e < 32; ++e) {
                    acc[eh + e] = fmaf(wrow[eh + e], xv, acc[eh + e]);
                }
            }
        }
    }

    // write partial logits: part[s][token][expert], 256B contiguous per lane
    float* dst = part + ((size_t)s * TOKENS + (t0 + lane)) * EXPERTS;
#pragma unroll
    for (int e = 0; e < EXPERTS; e += 4) {
        float4 v = make_float4(acc[e], acc[e + 1], acc[e + 2], acc[e + 3]);
        *reinterpret_cast<float4*>(dst + e) = v;
    }
}

// ---------------------------------------------------------------------------
// Kernel C: reduce partials -> softmax -> top-8 -> probs + routing map.
// One wave per token; lane = expert. Tie-break: lower index (lax.top_k).
// Block = 256 threads (4 waves/tokens per block), grid = TOKENS/4.
// ---------------------------------------------------------------------------
__global__ void reduce_topk_kernel(const float* __restrict__ part,
                                   float* __restrict__ out,
                                   int split) {
    const int wid = threadIdx.x >> 6;
    const int lane = threadIdx.x & 63;
    const int t = blockIdx.x * 4 + wid;

    float logit = 0.0f;
    for (int s = 0; s < split; ++s) {
        logit += part[((size_t)s * TOKENS + t) * EXPERTS + lane];
    }

    // softmax over the 64 lanes
    float m = logit;
#pragma unroll
    for (int off = 32; off >= 1; off >>= 1) m = fmaxf(m, __shfl_xor(m, off, 64));
    const float ex = __expf(logit - m);
    float sum = ex;
#pragma unroll
    for (int off = 32; off >= 1; off >>= 1) sum += __shfl_xor(sum, off, 64);
    const float score = ex / sum;

    // iterative top-8: argmax with (value desc, index asc) tie-break
    float v = score;
    bool sel = false;
#pragma unroll
    for (int it = 0; it < 8; ++it) {
        float bv = v;
        int bi = lane;
#pragma unroll
        for (int off = 32; off >= 1; off >>= 1) {
            const float ov = __shfl_xor(bv, off, 64);
            const int oi = __shfl_xor(bi, off, 64);
            if (ov > bv || (ov == bv && oi < bi)) { bv = ov; bi = oi; }
        }
        if (lane == bi) { sel = true; v = -1.0f; }  // scores are > 0
    }

    out[(size_t)t * EXPERTS + lane] = sel ? score : 0.0f;
    out[(size_t)TOKENS * EXPERTS + (size_t)t * EXPERTS + lane] = sel ? 1.0f : 0.0f;
}

// ---------------------------------------------------------------------------
extern "C" void kernel_launch(void* const* d_in, const int* in_sizes, int n_in,
                              void* d_out, int out_size, void* d_ws, size_t ws_size,
                              hipStream_t stream) {
    (void)in_sizes; (void)n_in; (void)out_size;
    const float* x = (const float*)d_in[0];       // [8192][4096] f32
    const float* w = (const float*)d_in[1];       // [64][4096] f32
    float* out = (float*)d_out;                   // probs [T][E] then map [T][E]

    float* wT = (float*)d_ws;                                     // 1 MB
    float* part = (float*)((char*)d_ws + (size_t)(1 << 20));      // split * 2 MB

    // choose K-split that fits the workspace (need 1MB + split*2MB)
    int split = 16;
    while (split > 1 &&
           (size_t)(1 << 20) + (size_t)split * TOKENS * EXPERTS * 4 > ws_size) {
        split >>= 1;
    }
    const int ks = HIDDEN / split;

    // A: transpose weight
    transpose_w_kernel<<<(EXPERTS * HIDDEN) / 256, 256, 0, stream>>>(w, wT);

    // B: partial logits
    logits_partial_kernel<<<(TOKENS / 64) * split, 64, 0, stream>>>(x, wT, part,
                                                                    split, ks);

    // C: reduce + softmax + top-8 + outputs
    reduce_topk_kernel<<<TOKENS / 4, 256, 0, stream>>>(part, out, split);
}